// Round 7
// baseline (846.134 us; speedup 1.0000x reference)
//
#include <hip/hip_runtime.h>
#include <hip/hip_bf16.h>
#include <stdint.h>

// ---- problem constants ----
#define NB   65536      // batch points
#define NC   2
#define NV   3
#define ND   64
#define NK   1024       // codebook entries
#define NS   4
#define NH   1024
#define NL   5
#define NF   25
#define NIN  102
#define K0P  128        // padded layer-0 K

typedef float f32x4 __attribute__((ext_vector_type(4)));
typedef int   i32x4 __attribute__((ext_vector_type(4)));
typedef int   i32x8 __attribute__((ext_vector_type(8)));
typedef unsigned char u8;

__device__ __forceinline__ void load_lds16(const void* g, void* l) {
    __builtin_amdgcn_global_load_lds(
        (const __attribute__((address_space(1))) void*)g,
        (__attribute__((address_space(3))) void*)l,
        16, 0, 0);
}

// fp8 e4m3 scalar convert (RNE, saturating): low byte of cvt_pk
__device__ __forceinline__ u8 to_fp8(float x) {
    return (u8)(__builtin_amdgcn_cvt_pk_fp8_f32(x, 0.0f, 0, false) & 0xff);
}

__device__ __forceinline__ f32x4 mfma128(i32x8 wf, i32x8 af, f32x4 c) {
    // swapped operands: D rows (q*4+r) = n-dim, cols (r16) = m-dim
    return __builtin_amdgcn_mfma_scale_f32_16x16x128_f8f6f4(
        wf, af, c, 0, 0,
        0, 0x79797979,    // scale src0 (W): 2^-6
        0, 0x7f7f7f7f);   // scale src1 (A): 2^0
}

// ===========================================================================
// TILED OPERAND LAYOUTS (unchanged from R17)
//  W_t: flat = (((bn*nIt + it)*8 + j)*2 + half)*1024 + (q*16+r16)*16 + b16
//       holds W[n][k]: n = bn*128 + j*16 + r16,
//                      k = it*128 + q*32 + half*16 + b16.
//       Per-(bn,it) slab = 16 KB contiguous; frag read = 2 x b128 at
//       lane*16 / +1024 (conflict-free).
//  A_t (half-split): flat = ((m16*nIt + it)*2 + half)*1024
//                          + (q*16+r16)*16 + b16
//       holds A[m][k]: m = m16*16 + r16, k = it*128 + q*32 + half*16 + b16.
//       Per-(m16,it) slab = 2 KB contiguous; frag = 2 x dwordx4 at lane*16 /
//       +1024, 64 lanes contiguous -> fully coalesced direct-global reads.
// ===========================================================================

// ---------------------------------------------------------------------------
// VQ kernel: single block, 1024 threads (one codebook row per thread). fp32.
// ---------------------------------------------------------------------------
__global__ __launch_bounds__(1024) void vq_kernel(
    const float* __restrict__ latents, const int* __restrict__ latent_idx,
    const float* __restrict__ codebooks, float* __restrict__ zq_out,
    float* __restrict__ out) {
    __shared__ float zcur[ND], resid[ND], zqsum[ND], ssq[ND];
    __shared__ float sDw[16];
    __shared__ int   sKw[16];
    __shared__ int   sBest;
    int t = threadIdx.x, lane = t & 63, wv = t >> 6;
    const float* img = latents + (size_t)latent_idx[0] * (NS * ND);
    if (t < ND) { resid[t] = 0.f; zqsum[t] = 0.f; }
    __syncthreads();
    float lossAcc = 0.f;   // thread 0 only
    for (int s = 0; s < NS; s++) {
        if (t < ND) {
            float iv = img[s * ND + t];
            float r  = resid[t] + iv;
            resid[t] = r;
            zcur[t]  = (s == 0) ? iv : (r - zqsum[t]);
        }
        __syncthreads();
        float zz = 0.f;
#pragma unroll
        for (int d = 0; d < ND; d++) { float z = zcur[d]; zz += z * z; }
        const float4* e4 = (const float4*)(codebooks + ((size_t)s * NK + t) * ND);
        float dot = 0.f, ee = 0.f;
#pragma unroll
        for (int i = 0; i < 16; i++) {
            float4 v = e4[i];
            dot += zcur[4 * i + 0] * v.x; dot += zcur[4 * i + 1] * v.y;
            dot += zcur[4 * i + 2] * v.z; dot += zcur[4 * i + 3] * v.w;
            ee  += v.x * v.x; ee += v.y * v.y; ee += v.z * v.z; ee += v.w * v.w;
        }
        float dmin = zz - 2.0f * dot + ee;
        int   kmin = t;
#pragma unroll
        for (int m = 1; m < 64; m <<= 1) {
            float d2 = __shfl_xor(dmin, m);
            int   k2 = __shfl_xor(kmin, m);
            if (d2 < dmin || (d2 == dmin && k2 < kmin)) { dmin = d2; kmin = k2; }
        }
        if (lane == 0) { sDw[wv] = dmin; sKw[wv] = kmin; }
        __syncthreads();
        if (t == 0) {
            float bd = sDw[0]; int bk = sKw[0];
            for (int w = 1; w < 16; w++) {
                float d2 = sDw[w]; int k2 = sKw[w];
                if (d2 < bd || (d2 == bd && k2 < bk)) { bd = d2; bk = k2; }
            }
            sBest = bk;
            out[NB * NV + s] = (float)bk;
        }
        __syncthreads();
        int best = sBest;
        const float* eb = codebooks + ((size_t)s * NK + best) * ND;
        if (t < ND) {
            float zq = eb[t];
            float d  = zq - zcur[t];
            ssq[t]   = d * d;
            zqsum[t] = zqsum[t] + (zq + (zcur[t] - zq));   // z_q_st forward (exact ref arith)
        }
        __syncthreads();
        if (t == 0) {
            float sum = 0.f;
            for (int d = 0; d < ND; d++) sum += ssq[d];
            lossAcc += 0.25f * (sum / (float)ND);
        }
    }
    if (t < ND) zq_out[t] = zqsum[t];
    if (t == 0) out[NB * NV + NS] = lossAcc;
}

// ---------------------------------------------------------------------------
// betas fused with decoder biases (fp32)
// ---------------------------------------------------------------------------
__global__ __launch_bounds__(256) void betas_kernel(
    const float* __restrict__ zq, const float* __restrict__ mod_W,
    const float* __restrict__ mod_b, const float* __restrict__ b0,
    const float* __restrict__ bh, float* __restrict__ bb) {
    int g = blockIdx.x * 256 + threadIdx.x;   // < 5120
    int l = g >> 10, n = g & 1023;
    float acc = mod_b[g];
    for (int d = 0; d < ND; d++) acc += zq[d] * mod_W[(size_t)(l * ND + d) * NH + n];
    acc += (l == 0) ? b0[n] : bh[(size_t)(l - 1) * NH + n];
    bb[g] = acc;
}

// ---------------------------------------------------------------------------
// out init: values[m][v] = bout[v] (atomic-add target for the fused layer)
// ---------------------------------------------------------------------------
__global__ __launch_bounds__(256) void init_out_kernel(
    const float* __restrict__ bout, float* __restrict__ out) {
    int g = blockIdx.x * 256 + threadIdx.x;   // < NB*NV
    out[g] = bout[g % NV];
}

// ---------------------------------------------------------------------------
// Weight prep: fp32 [Ks][1024] -> fp8 e4m3 W_t tiled (x64, undone by the
// MFMA e8m0 scale 2^-6). Zero-pad k>=Ks. nIt = Kp/128. Half-split layout.
// ---------------------------------------------------------------------------
__global__ __launch_bounds__(256) void prep_kernel(
    const float* __restrict__ src, u8* __restrict__ dst, int Ks, int Kp) {
    __shared__ float tile[32][33];
    int nIt = Kp >> 7;
    src += (size_t)blockIdx.z * Ks * NH;
    dst += (size_t)blockIdx.z * NH * Kp;
    int k0 = blockIdx.x * 32, n0 = blockIdx.y * 32;
    int tx = threadIdx.x, ty = threadIdx.y;   // (32, 8)
    for (int i = 0; i < 4; i++) {
        int k = k0 + ty + i * 8;
        int n = n0 + tx;
        tile[ty + i * 8][tx] = (k < Ks) ? src[(size_t)k * NH + n] : 0.0f;
    }
    __syncthreads();
    for (int i = 0; i < 4; i++) {
        int n = n0 + ty + i * 8;
        int k = k0 + tx;
        int bn = n >> 7, j = (n >> 4) & 7, r16 = n & 15;
        int it = k >> 7, q = (k >> 5) & 3, half = (k >> 4) & 1, b16 = k & 15;
        size_t flat = ((size_t)(((bn * nIt + it) * 8 + j) * 2 + half)) * 1024
                    + (q * 16 + r16) * 16 + b16;
        dst[flat] = to_fp8(tile[tx][ty + i * 8] * 64.0f);
    }
}

// ---------------------------------------------------------------------------
// Positional encoding -> fp8 A_t (half-split layout, K=128, nIt=1)
// ---------------------------------------------------------------------------
__device__ __forceinline__ float pe_val(const float* coords, int m, int k) {
    if (k < 2) return coords[m * 2 + k];
    if (k >= NIN) return 0.0f;
    int u = k - 2;
    int f = u >> 2, r = u & 3;
    float c = coords[m * 2 + (r & 1)];
    float a = c * __builtin_ldexpf(3.14159274101257324f, f);
    return (r < 2) ? sinf(a) : cosf(a);
}

__global__ __launch_bounds__(256) void pe_kernel(
    const float* __restrict__ coords, u8* __restrict__ pe) {
    int g = blockIdx.x * 256 + threadIdx.x;   // < Bc*32
    int m = g >> 5, k4 = (g & 31) * 4;
    float v0 = pe_val(coords, m, k4 + 0);
    float v1 = pe_val(coords, m, k4 + 1);
    float v2 = pe_val(coords, m, k4 + 2);
    float v3 = pe_val(coords, m, k4 + 3);
    int p = __builtin_amdgcn_cvt_pk_fp8_f32(v0, v1, 0, false);
    p     = __builtin_amdgcn_cvt_pk_fp8_f32(v2, v3, p, true);
    // A_t half-split (nIt=1): ((m16*1+0)*2 + half)*1024 + (q*16+r16)*16 + b16
    int m16 = m >> 4, r16 = m & 15;
    int q = k4 >> 5, half = (k4 >> 4) & 1, b16 = k4 & 15;
    *(int*)(pe + ((size_t)(m16 * 2 + half)) * 1024 + (q * 16 + r16) * 16 + b16) = p;
}

// ---------------------------------------------------------------------------
// MX-fp8 MFMA GEMM, R19: MAX-TLP simple loop (R18 + the missing prologue
// barrier). R18's absmax 1349 was a race: iter 0 read W-buffer 0 while its
// global_load_lds ops were still in flight (gload_lds counts in vmcnt; the
// compiler does NOT model gload_lds -> ds_read dependencies; every passing
// round had a barrier between stage and first read). The end-of-iter
// __syncthreads (vmcnt(0)+lgkmcnt(0) drain) covers W(it+1) for it>=1 and the
// WAR hazard on buffer reuse; only tile 0 was unprotected.
// Structure (unchanged from R18): 256m x 128n block, 8 waves as 4m x 2n,
// wave tile 64x64 (acc[4][4] = 64 AGPR), __launch_bounds__(512, 4) =>
// <=128 regs/wave => 2 blocks/CU = 16 waves/CU = 4 waves/SIMD (~50% occ,
// 2x all previous rounds). W via 32 KB LDS double-buffer (static LDS,
// 64 KB/CU at 2 blocks); A-frags DIRECT global->reg (no A staging - TLP
// hides L2 latency). One __syncthreads per iter, no inline-asm waitcnts:
// fully compiler-managed (the only spill-safe regime this session).
// MODE 0: relu(acc+bb) -> fp8, repack to next layer's A_t via LDS, coalesced.
// MODE 1: out[m][v] += relu(acc+bb).Wout[n][v], q-shfl + LDS wn-reduce.
// ---------------------------------------------------------------------------
template <int MODE, int KT>
__global__ __launch_bounds__(512, 4) void gemm_kernel(
    const u8* __restrict__ A, const u8* __restrict__ W,
    const float* __restrict__ bb, u8* __restrict__ O,
    const float* __restrict__ Wout, float* __restrict__ out, int Mb) {
    __shared__ __align__(16) u8 smem[32768];   // W double buffer (2 x 16 KB)
    int t   = threadIdx.x;
    int fid = blockIdx.x;
    int xcd = fid & 7;
    int j8  = fid >> 3;                 // 0..Mb-1
    int bn  = j8 & 7;                   // fastest within an XCD
    int bm  = xcd * (Mb >> 3) + (j8 >> 3);   // 256-row m-tile index
    int lane = t & 63, w = t >> 6;      // 8 waves
    int wm4  = w >> 1, wn = w & 1;      // 4 m-quarters x 2 n-halves
    int q    = lane >> 4, r16 = lane & 15;
    constexpr int nIt = KT >> 7;

    const u8* wslab = W + (size_t)(bn * nIt) * 16384;
    // A_t base for this wave's 4 m16-groups
    const u8* abase = A + (size_t)(bm * 16 + wm4 * 4) * (nIt * 2048) + lane * 16;

    f32x4 acc[4][4];
    f32x4 zero = {0.f, 0.f, 0.f, 0.f};
#pragma unroll
    for (int i = 0; i < 4; i++)
#pragma unroll
        for (int j = 0; j < 4; j++) acc[i][j] = zero;

    // stage W K-tile `it` into LDS buffer (it&1): 16 KB = 2 x 512 thr x 16 B
#define STAGE_W(IT)                                                            \
    {                                                                          \
        u8* dst_ = smem + ((IT) & 1) * 16384;                                  \
        load_lds16((const void*)(wslab + (size_t)(IT) * 16384 + t * 16),       \
                   (void*)(dst_ + t * 16));                                    \
        load_lds16((const void*)(wslab + (size_t)(IT) * 16384 + 8192 + t * 16),\
                   (void*)(dst_ + 8192 + t * 16));                             \
    }
#define LDPAIR_L(dst, base)                                                    \
    {                                                                          \
        i32x4 lo_ = *(const i32x4*)(base);                                     \
        i32x4 hi_ = *(const i32x4*)((base) + 1024);                            \
        dst = __builtin_shufflevector(lo_, hi_, 0, 1, 2, 3, 4, 5, 6, 7);       \
    }

    // ---- prologue: stage W(0), DRAIN before first read (R18's missing
    // barrier: gload_lds->ds_read dependency is not compiler-tracked) ----
    STAGE_W(0)
    __syncthreads();

#pragma unroll
    for (int it = 0; it < nIt; it++) {
        // issue next W stage first (drained by the end-of-iter syncthreads,
        // mostly covered by this iter's compute)
        if (it + 1 < nIt) STAGE_W(it + 1)

        // A fragments for this K-tile: direct global (coalesced 1 KB/instr)
        i32x8 a0, a1, a2, a3;
        LDPAIR_L(a0, abase + (size_t)(0 * nIt + it) * 2048)
        LDPAIR_L(a1, abase + (size_t)(1 * nIt + it) * 2048)
        LDPAIR_L(a2, abase + (size_t)(2 * nIt + it) * 2048)
        LDPAIR_L(a3, abase + (size_t)(3 * nIt + it) * 2048)

        const u8* Wb = smem + (it & 1) * 16384;
        {
            i32x8 w0, w1;
            LDPAIR_L(w0, Wb + (wn * 4 + 0) * 2048 + lane * 16)
            LDPAIR_L(w1, Wb + (wn * 4 + 1) * 2048 + lane * 16)
            acc[0][0] = mfma128(w0, a0, acc[0][0]);
            acc[1][0] = mfma128(w0, a1, acc[1][0]);
            acc[2][0] = mfma128(w0, a2, acc[2][0]);
            acc[3][0] = mfma128(w0, a3, acc[3][0]);
            acc[0][1] = mfma128(w1, a0, acc[0][1]);
            acc[1][1] = mfma128(w1, a1, acc[1][1]);
            acc[2][1] = mfma128(w1, a2, acc[2][1]);
            acc[3][1] = mfma128(w1, a3, acc[3][1]);
        }
        {
            i32x8 w2, w3;
            LDPAIR_L(w2, Wb + (wn * 4 + 2) * 2048 + lane * 16)
            LDPAIR_L(w3, Wb + (wn * 4 + 3) * 2048 + lane * 16)
            acc[0][2] = mfma128(w2, a0, acc[0][2]);
            acc[1][2] = mfma128(w2, a1, acc[1][2]);
            acc[2][2] = mfma128(w2, a2, acc[2][2]);
            acc[3][2] = mfma128(w2, a3, acc[3][2]);
            acc[0][3] = mfma128(w3, a0, acc[0][3]);
            acc[1][3] = mfma128(w3, a1, acc[1][3]);
            acc[2][3] = mfma128(w3, a2, acc[2][3]);
            acc[3][3] = mfma128(w3, a3, acc[3][3]);
        }
        __syncthreads();
    }
#undef STAGE_W
#undef LDPAIR_L

    // lane element (i,j,r): m = bm*256 + wm4*64 + i*16 + r16,
    //                       n = bn*128 + (wn*4 + j)*16 + q*4 + r
    if constexpr (MODE == 0) {
        // Repack to next layer's A_t (half-split, nIt'=8, it'=bn).
        // Local 32 KB: [m16l(16)][half(2)][1024B], inner (q'*16+r16)*16+b16.
        u8* eb = smem;
#pragma unroll
        for (int i = 0; i < 4; i++) {
#pragma unroll
            for (int j = 0; j < 4; j++) {
                int nl = (wn * 4 + j) * 16 + q * 4;
                f32x4 b4 = *(const f32x4*)(bb + bn * 128 + nl);
                float v0 = fmaxf(acc[i][j][0] + b4[0], 0.0f);
                float v1 = fmaxf(acc[i][j][1] + b4[1], 0.0f);
                float v2 = fmaxf(acc[i][j][2] + b4[2], 0.0f);
                float v3 = fmaxf(acc[i][j][3] + b4[3], 0.0f);
                int p = __builtin_amdgcn_cvt_pk_fp8_f32(v0, v1, 0, false);
                p     = __builtin_amdgcn_cvt_pk_fp8_f32(v2, v3, p, true);
                int m16l = wm4 * 4 + i;
                int half = j & 1;
                int qp   = wn * 2 + (j >> 1);      // (n>>5)&3
                int idx  = (m16l * 2 + half) * 1024 + (qp * 16 + r16) * 16 + q * 4;
                *(int*)(eb + idx) = p;
            }
        }
        __syncthreads();
#pragma unroll
        for (int rd = 0; rd < 4; rd++) {
            int g2 = rd * 512 + t;                 // dwordx4 index 0..2047
            i32x4 v = *(const i32x4*)(eb + g2 * 16);
            *(i32x4*)(O + ((size_t)((bm * 16 + (g2 >> 7)) * 8 + bn)) * 2048
                      + (g2 & 127) * 16) = v;
        }
    } else {
        float* red = (float*)smem;                 // [256][2][3] = 6 KB
#pragma unroll
        for (int i = 0; i < 4; i++) {
            float p0 = 0.f, p1 = 0.f, p2 = 0.f;
#pragma unroll
            for (int j = 0; j < 4; j++) {
                int nb = bn * 128 + (wn * 4 + j) * 16 + q * 4;
                f32x4 b4 = *(const f32x4*)(bb + nb);
#pragma unroll
                for (int r = 0; r < 4; r++) {
                    float val = fmaxf(acc[i][j][r] + b4[r], 0.0f);
                    const float* wo = Wout + (size_t)(nb + r) * NV;
                    p0 += val * wo[0]; p1 += val * wo[1]; p2 += val * wo[2];
                }
            }
            // reduce over the 4 q-lanes (lane bits 4,5) holding the same m
            p0 += __shfl_xor(p0, 16); p0 += __shfl_xor(p0, 32);
            p1 += __shfl_xor(p1, 16); p1 += __shfl_xor(p1, 32);
            p2 += __shfl_xor(p2, 16); p2 += __shfl_xor(p2, 32);
            if (q == 0) {
                int row = (wm4 * 4 + i) * 16 + r16;   // 0..255
                int base = (row * 2 + wn) * 3;
                red[base + 0] = p0; red[base + 1] = p1; red[base + 2] = p2;
            }
        }
        __syncthreads();
        if (t < 256) {
            float s0 = red[(t * 2 + 0) * 3 + 0] + red[(t * 2 + 1) * 3 + 0];
            float s1 = red[(t * 2 + 0) * 3 + 1] + red[(t * 2 + 1) * 3 + 1];
            float s2 = red[(t * 2 + 0) * 3 + 2] + red[(t * 2 + 1) * 3 + 2];
            int m = bm * 256 + t;
            atomicAdd(&out[(size_t)m * NV + 0], s0);
            atomicAdd(&out[(size_t)m * NV + 1], s1);
            atomicAdd(&out[(size_t)m * NV + 2], s2);
        }
    }
}

// ---------------------------------------------------------------------------
extern "C" void kernel_launch(void* const* d_in, const int* in_sizes, int n_in,
                              void* d_out, int out_size, void* d_ws, size_t ws_size,
                              hipStream_t stream) {
    const float* coords     = (const float*)d_in[0];
    const int*   latent_idx = (const int*)d_in[1];
    const float* latents    = (const float*)d_in[2];
    const float* codebooks  = (const float*)d_in[3];
    const float* mod_W      = (const float*)d_in[4];
    const float* mod_b      = (const float*)d_in[5];
    const float* dec_W0     = (const float*)d_in[6];
    const float* dec_b0     = (const float*)d_in[7];
    const float* dec_Wh     = (const float*)d_in[8];
    const float* dec_bh     = (const float*)d_in[9];
    const float* dec_Wout   = (const float*)d_in[10];
    const float* dec_bout   = (const float*)d_in[11];
    float* out = (float*)d_out;

    // ---- workspace layout (fixed part ~4.35 MB) ----
    char* wsb = (char*)d_ws;
    float* zq  = (float*)(wsb + 0);                        //      256 B
    float* bb  = (float*)(wsb + 256);                      //   20,480 B
    u8*    W0T = (u8*)(wsb + 20736);                       //  131,072 B  tiled
    u8*    WhT = (u8*)(wsb + 151808);                      // 4,194,304 B tiled
    const size_t fixed_end = 4346368;                      // 256-aligned

    // adaptive chunk: cap 65536 (single chunk, ws ~139 MB), halve until fits;
    // floor 2048 so Mb = Bc/256 stays a multiple of 8 (capture-safe).
    int Bc = 65536;
    while (Bc > 2048 && fixed_end + 2 * (size_t)Bc * NH > ws_size)
        Bc >>= 1;
    int Mb = Bc / 256;   // m-tiles of 256

    u8* hA = (u8*)(wsb + fixed_end);                       // [Bc][1024] fp8 A_t
    u8* hB = hA + (size_t)Bc * NH;                         // [Bc][1024] fp8 A_t
    u8* pe = hB;   // pe A_t [Bc][128] aliases hB (dead before layer-1 writes hB)

    // ---- one-time (per call) small kernels ----
    vq_kernel<<<1, 1024, 0, stream>>>(latents, latent_idx, codebooks, zq, out);
    betas_kernel<<<20, 256, 0, stream>>>(zq, mod_W, mod_b, dec_b0, dec_bh, bb);
    init_out_kernel<<<(NB * NV) / 256, 256, 0, stream>>>(dec_bout, out);
    prep_kernel<<<dim3(4, 32, 1), dim3(32, 8), 0, stream>>>(dec_W0, W0T, NIN, K0P);
    prep_kernel<<<dim3(32, 32, 4), dim3(32, 8), 0, stream>>>(dec_Wh, WhT, NH, NH);

    // ---- chunked 5-layer MLP, output layer fused into the last GEMM ----
    for (int c0 = 0; c0 < NB; c0 += Bc) {
        pe_kernel<<<(Bc * 32) / 256, 256, 0, stream>>>(coords + (size_t)c0 * NC, pe);
        gemm_kernel<0, K0P><<<8 * Mb, 512, 0, stream>>>(
            pe, W0T, bb + 0 * NH, hA, nullptr, nullptr, Mb);
        gemm_kernel<0, NH><<<8 * Mb, 512, 0, stream>>>(
            hA, WhT + 0 * (size_t)NH * NH, bb + 1 * NH, hB, nullptr, nullptr, Mb);
        gemm_kernel<0, NH><<<8 * Mb, 512, 0, stream>>>(
            hB, WhT + 1 * (size_t)NH * NH, bb + 2 * NH, hA, nullptr, nullptr, Mb);
        gemm_kernel<0, NH><<<8 * Mb, 512, 0, stream>>>(
            hA, WhT + 2 * (size_t)NH * NH, bb + 3 * NH, hB, nullptr, nullptr, Mb);
        gemm_kernel<1, NH><<<8 * Mb, 512, 0, stream>>>(
            hB, WhT + 3 * (size_t)NH * NH, bb + 4 * NH, nullptr,
            dec_Wout, out + (size_t)c0 * NV, Mb);
    }
}

// Round 8
// 784.248 us; speedup vs baseline: 1.0789x; 1.0789x over previous
//
#include <hip/hip_runtime.h>
#include <hip/hip_bf16.h>
#include <stdint.h>

// ---- problem constants ----
#define NB   65536      // batch points
#define NC   2
#define NV   3
#define ND   64
#define NK   1024       // codebook entries
#define NS   4
#define NH   1024
#define NL   5
#define NF   25
#define NIN  102
#define K0P  128        // padded layer-0 K

typedef float f32x4 __attribute__((ext_vector_type(4)));
typedef int   i32x4 __attribute__((ext_vector_type(4)));
typedef int   i32x8 __attribute__((ext_vector_type(8)));
typedef unsigned char u8;

__device__ __forceinline__ void load_lds16(const void* g, void* l) {
    __builtin_amdgcn_global_load_lds(
        (const __attribute__((address_space(1))) void*)g,
        (__attribute__((address_space(3))) void*)l,
        16, 0, 0);
}

// fp8 e4m3 scalar convert (RNE, saturating): low byte of cvt_pk
__device__ __forceinline__ u8 to_fp8(float x) {
    return (u8)(__builtin_amdgcn_cvt_pk_fp8_f32(x, 0.0f, 0, false) & 0xff);
}

// ===========================================================================
// TILED OPERAND LAYOUTS (R12, restored verbatim)
//  W_t: flat = (((bn*nIt + it)*8 + j)*2 + half)*1024 + (q*16+r16)*16 + b16
//       holds W[n][k]: n = bn*128 + j*16 + r16, k = it*128 + q*32 + half*16 + b16.
//       Per-(bn,it) slab = 16 KB contiguous -> global_load_lds staging;
//       frag ds_read = 2x b128 at stride-16 (conflict-free). Slabs it, it+1
//       are CONTIGUOUS 32 KB -> pair-staging is one linear 32 KB copy.
//  A_t: flat = ((m16*(K/32) + c32)*16 + r)*32 + b
//       holds A[m][k]: m = m16*16 + r, k = c32*32 + b. Direct-global frags.
// ===========================================================================

// ---------------------------------------------------------------------------
// VQ kernel: single block, 1024 threads (one codebook row per thread). fp32.
// ---------------------------------------------------------------------------
__global__ __launch_bounds__(1024) void vq_kernel(
    const float* __restrict__ latents, const int* __restrict__ latent_idx,
    const float* __restrict__ codebooks, float* __restrict__ zq_out,
    float* __restrict__ out) {
    __shared__ float zcur[ND], resid[ND], zqsum[ND], ssq[ND];
    __shared__ float sDw[16];
    __shared__ int   sKw[16];
    __shared__ int   sBest;
    int t = threadIdx.x, lane = t & 63, wv = t >> 6;
    const float* img = latents + (size_t)latent_idx[0] * (NS * ND);
    if (t < ND) { resid[t] = 0.f; zqsum[t] = 0.f; }
    __syncthreads();
    float lossAcc = 0.f;   // thread 0 only
    for (int s = 0; s < NS; s++) {
        if (t < ND) {
            float iv = img[s * ND + t];
            float r  = resid[t] + iv;
            resid[t] = r;
            zcur[t]  = (s == 0) ? iv : (r - zqsum[t]);
        }
        __syncthreads();
        float zz = 0.f;
#pragma unroll
        for (int d = 0; d < ND; d++) { float z = zcur[d]; zz += z * z; }
        const float4* e4 = (const float4*)(codebooks + ((size_t)s * NK + t) * ND);
        float dot = 0.f, ee = 0.f;
#pragma unroll
        for (int i = 0; i < 16; i++) {
            float4 v = e4[i];
            dot += zcur[4 * i + 0] * v.x; dot += zcur[4 * i + 1] * v.y;
            dot += zcur[4 * i + 2] * v.z; dot += zcur[4 * i + 3] * v.w;
            ee  += v.x * v.x; ee += v.y * v.y; ee += v.z * v.z; ee += v.w * v.w;
        }
        float dmin = zz - 2.0f * dot + ee;
        int   kmin = t;
#pragma unroll
        for (int m = 1; m < 64; m <<= 1) {
            float d2 = __shfl_xor(dmin, m);
            int   k2 = __shfl_xor(kmin, m);
            if (d2 < dmin || (d2 == dmin && k2 < kmin)) { dmin = d2; kmin = k2; }
        }
        if (lane == 0) { sDw[wv] = dmin; sKw[wv] = kmin; }
        __syncthreads();
        if (t == 0) {
            float bd = sDw[0]; int bk = sKw[0];
            for (int w = 1; w < 16; w++) {
                float d2 = sDw[w]; int k2 = sKw[w];
                if (d2 < bd || (d2 == bd && k2 < bk)) { bd = d2; bk = k2; }
            }
            sBest = bk;
            out[NB * NV + s] = (float)bk;
        }
        __syncthreads();
        int best = sBest;
        const float* eb = codebooks + ((size_t)s * NK + best) * ND;
        if (t < ND) {
            float zq = eb[t];
            float d  = zq - zcur[t];
            ssq[t]   = d * d;
            zqsum[t] = zqsum[t] + (zq + (zcur[t] - zq));   // z_q_st forward (exact ref arith)
        }
        __syncthreads();
        if (t == 0) {
            float sum = 0.f;
            for (int d = 0; d < ND; d++) sum += ssq[d];
            lossAcc += 0.25f * (sum / (float)ND);
        }
    }
    if (t < ND) zq_out[t] = zqsum[t];
    if (t == 0) out[NB * NV + NS] = lossAcc;
}

// ---------------------------------------------------------------------------
// betas fused with decoder biases (fp32)
// ---------------------------------------------------------------------------
__global__ __launch_bounds__(256) void betas_kernel(
    const float* __restrict__ zq, const float* __restrict__ mod_W,
    const float* __restrict__ mod_b, const float* __restrict__ b0,
    const float* __restrict__ bh, float* __restrict__ bb) {
    int g = blockIdx.x * 256 + threadIdx.x;   // < 5120
    int l = g >> 10, n = g & 1023;
    float acc = mod_b[g];
    for (int d = 0; d < ND; d++) acc += zq[d] * mod_W[(size_t)(l * ND + d) * NH + n];
    acc += (l == 0) ? b0[n] : bh[(size_t)(l - 1) * NH + n];
    bb[g] = acc;
}

// ---------------------------------------------------------------------------
// out init: values[m][v] = bout[v] (atomic-add target for the fused layer)
// ---------------------------------------------------------------------------
__global__ __launch_bounds__(256) void init_out_kernel(
    const float* __restrict__ bout, float* __restrict__ out) {
    int g = blockIdx.x * 256 + threadIdx.x;   // < NB*NV
    out[g] = bout[g % NV];
}

// ---------------------------------------------------------------------------
// Weight prep: fp32 [Ks][1024] -> fp8 e4m3 W_t tiled (x64, undone by the
// MFMA e8m0 scale 2^-6). Zero-pad k>=Ks. nIt = Kp/128. Half-split layout.
// ---------------------------------------------------------------------------
__global__ __launch_bounds__(256) void prep_kernel(
    const float* __restrict__ src, u8* __restrict__ dst, int Ks, int Kp) {
    __shared__ float tile[32][33];
    int nIt = Kp >> 7;
    src += (size_t)blockIdx.z * Ks * NH;
    dst += (size_t)blockIdx.z * NH * Kp;
    int k0 = blockIdx.x * 32, n0 = blockIdx.y * 32;
    int tx = threadIdx.x, ty = threadIdx.y;   // (32, 8)
    for (int i = 0; i < 4; i++) {
        int k = k0 + ty + i * 8;
        int n = n0 + tx;
        tile[ty + i * 8][tx] = (k < Ks) ? src[(size_t)k * NH + n] : 0.0f;
    }
    __syncthreads();
    for (int i = 0; i < 4; i++) {
        int n = n0 + ty + i * 8;
        int k = k0 + tx;
        int bn = n >> 7, j = (n >> 4) & 7, r16 = n & 15;
        int it = k >> 7, q = (k >> 5) & 3, half = (k >> 4) & 1, b16 = k & 15;
        size_t flat = ((size_t)(((bn * nIt + it) * 8 + j) * 2 + half)) * 1024
                    + (q * 16 + r16) * 16 + b16;
        dst[flat] = to_fp8(tile[tx][ty + i * 8] * 64.0f);
    }
}

// ---------------------------------------------------------------------------
// Positional encoding -> fp8 A_t tiled [Bc][128] (K/32 = 4 chunks)  [R12 form]
// ---------------------------------------------------------------------------
__device__ __forceinline__ float pe_val(const float* coords, int m, int k) {
    if (k < 2) return coords[m * 2 + k];
    if (k >= NIN) return 0.0f;
    int u = k - 2;
    int f = u >> 2, r = u & 3;
    float c = coords[m * 2 + (r & 1)];
    float a = c * __builtin_ldexpf(3.14159274101257324f, f);
    return (r < 2) ? sinf(a) : cosf(a);
}

__global__ __launch_bounds__(256) void pe_kernel(
    const float* __restrict__ coords, u8* __restrict__ pe) {
    int g = blockIdx.x * 256 + threadIdx.x;   // < Bc*32
    int m = g >> 5, k4 = (g & 31) * 4;
    float v0 = pe_val(coords, m, k4 + 0);
    float v1 = pe_val(coords, m, k4 + 1);
    float v2 = pe_val(coords, m, k4 + 2);
    float v3 = pe_val(coords, m, k4 + 3);
    int p = __builtin_amdgcn_cvt_pk_fp8_f32(v0, v1, 0, false);
    p     = __builtin_amdgcn_cvt_pk_fp8_f32(v2, v3, p, true);
    // A_t (K=128): flat = ((m16*4 + c32)*16 + r)*32 + b
    int m16 = m >> 4, r = m & 15, c32 = k4 >> 5, b = k4 & 31;
    *(int*)(pe + ((size_t)(m16 * 4 + c32) * 16 + r) * 32 + b) = p;
}

// ---------------------------------------------------------------------------
// MX-fp8 MFMA GEMM, R20: R12 structure with PAIRED W staging (barrier cadence
// halved). R12/R15/R17 all pinned at MfmaUtil 25-30%; R19 proved >=2 waves/
// SIMD is register-infeasible (~150+ live regs). Remaining un-tested lever on
// the verified R12 base: the once-per-128-K full vmcnt(0)+lgkmcnt(0) drain.
// R20 stages W in 32 KB PAIRS (slabs it, it+1 are contiguous in W_t) into a
// 2 x 32 KB LDS double-buffer and barriers once per 256 K:
//   pair pr: [load afB(A it=2pr+1); stage pair pr+1 (8 gload_lds)]
//            MFMA x16 on slab(2pr) with afA
//            [load afA(A it=2pr+2)]
//            MFMA x16 on slab(2pr+1) with afB
//            __syncthreads   (ONE drain per 256 K; stage issued ~2 MFMA
//                             blocks earlier -> well hidden)
// afA/afB alternate naturally within the pair: no copies, same 64 VGPR as
// R12. A-load program order BEFORE stage ops keeps the compiler's implicit
// vmcnt for afB at ~8 (stage stays in flight). Everything else (fragment
// paths, layouts, epilogues, 256 threads / 4 waves, launch_bounds(256,2))
// is R12 verbatim. LDS 64 KB static -> still 2 blocks/CU (128 KB of 160).
// MODE 0: relu(acc+bb) -> fp8, repack to next layer's A_t via LDS, coalesced.
// MODE 1: out[m][v] += relu(acc+bb).Wout[n][v], q-lane shfl + atomicAdd.
// ---------------------------------------------------------------------------
template <int MODE, int KT>
__global__ __launch_bounds__(256, 2) void gemm_kernel(
    const u8* __restrict__ A, const u8* __restrict__ W,
    const float* __restrict__ bb, u8* __restrict__ O,
    const float* __restrict__ Wout, float* __restrict__ out, int Mb) {
    __shared__ __align__(16) u8 smem[65536];
    int t   = threadIdx.x;
    int fid = blockIdx.x;
    int xcd = fid & 7;
    int j8  = fid >> 3;                 // 0..Mb-1
    int bn  = j8 & 7;                   // fastest within an XCD
    int bm  = xcd * (Mb >> 3) + (j8 >> 3);
    int lane = t & 63, wm = t >> 6;     // wave owns m-slice wm*64..+63
    int q    = lane >> 4, r16 = lane & 15;
    constexpr int nIt = KT >> 7;

    const u8* wslab = W + (size_t)(bn * nIt) * 16384;
    const u8* abase = A + ((size_t)(bm * 16 + wm * 4) * (KT >> 5)) * 512 + lane * 32;

    f32x4 acc[4][8];
    f32x4 zero = {0.f, 0.f, 0.f, 0.f};
    for (int i = 0; i < 4; i++)
        for (int j = 0; j < 8; j++) acc[i][j] = zero;

#define LOAD_AFRAG(dst, IT)                                                    \
    {                                                                          \
        _Pragma("unroll")                                                      \
        for (int i = 0; i < 4; i++) {                                          \
            const u8* p = abase + ((size_t)i * (KT >> 5) + (IT) * 4) * 512;    \
            i32x4 lo = *(const i32x4*)(p);                                     \
            i32x4 hi = *(const i32x4*)(p + 16);                                \
            dst[i] = __builtin_shufflevector(lo, hi, 0, 1, 2, 3, 4, 5, 6, 7);  \
        }                                                                      \
    }
#define MFMA_SLAB(base, af)                                                    \
    {                                                                          \
        _Pragma("unroll")                                                      \
        for (int j = 0; j < 8; j++) {                                          \
            i32x4 lo = *(const i32x4*)((base) + j * 2048 + lane * 16);         \
            i32x4 hi = *(const i32x4*)((base) + j * 2048 + 1024 + lane * 16);  \
            i32x8 bfr = __builtin_shufflevector(lo, hi, 0, 1, 2, 3, 4, 5, 6, 7);\
            _Pragma("unroll")                                                  \
            for (int i = 0; i < 4; i++)                                        \
                acc[i][j] = __builtin_amdgcn_mfma_scale_f32_16x16x128_f8f6f4(  \
                    bfr, af[i], acc[i][j], 0, 0,                               \
                    0, 0x79797979,    /* scale src0 (W): 2^-6 */               \
                    0, 0x7f7f7f7f);   /* scale src1 (A): 2^0  */               \
        }                                                                      \
    }

    if constexpr (nIt == 1) {
        // ---- K0P path: identical to R12 ----
#pragma unroll
        for (int p = 0; p < 4; p++) {
            int g = p * 256 + t;
            load_lds16((const void*)(wslab + g * 16), (void*)(smem + g * 16));
        }
        i32x8 afA[4];
        LOAD_AFRAG(afA, 0)
        __syncthreads();   // drains W staging + A loads
        MFMA_SLAB(smem, afA)
        __syncthreads();
    } else {
        // ---- prologue: stage pair 0 (slabs 0,1 = 32 KB contiguous);
        //      load afA (it=0) ----
        i32x8 afA[4], afB[4];
        LOAD_AFRAG(afA, 0)
        asm volatile("" ::: "memory");
#pragma unroll
        for (int p = 0; p < 8; p++) {
            int g = p * 256 + t;
            load_lds16((const void*)(wslab + g * 16), (void*)(smem + g * 16));
        }
        __syncthreads();   // drains everything: pair 0 + afA ready

#pragma unroll 1
        for (int pr = 0; pr < nIt / 2; pr++) {
            u8* bufc = smem + ((pr & 1) ? 32768 : 0);
            u8* bufn = smem + ((pr & 1) ? 0 : 32768);
            int it0 = 2 * pr;
            // sub-even: load afB (A it0+1) FIRST (so its implicit wait leaves
            // the younger stage ops in flight), then stage pair pr+1.
            LOAD_AFRAG(afB, it0 + 1)
            asm volatile("" ::: "memory");
            if (pr + 1 < nIt / 2) {
                const u8* ws = wslab + (size_t)(it0 + 2) * 16384;
#pragma unroll
                for (int p = 0; p < 8; p++) {
                    int g = p * 256 + t;
                    load_lds16((const void*)(ws + g * 16), (void*)(bufn + g * 16));
                }
            }
            MFMA_SLAB(bufc, afA)
            // sub-odd: prefetch afA for next pair (consumed after the barrier)
            if (pr + 1 < nIt / 2) {
                LOAD_AFRAG(afA, it0 + 2)
            }
            MFMA_SLAB(bufc + 16384, afB)
            __syncthreads();   // ONE drain per 256 K: pair pr+1 + afA landed,
                               // bufc reads complete (WAR-safe for restage)
        }
    }
#undef LOAD_AFRAG
#undef MFMA_SLAB

    // lane element (i,j,r): m = bm*256+wm*64+i*16+r16, n = bn*128+j*16+q*4+r
    if constexpr (MODE == 0) {
        // Repack to next layer's A_t (K=1024, 32 chunks/m16). Local LDS tile:
        // [m16_l(16)][c32_l(4)][r(16)][32B].
        u8* eb = smem;
#pragma unroll
        for (int i = 0; i < 4; i++) {
#pragma unroll
            for (int j = 0; j < 8; j++) {
                int nl = j * 16 + q * 4;
                f32x4 b4 = *(const f32x4*)(bb + bn * 128 + nl);
                float v0 = fmaxf(acc[i][j][0] + b4[0], 0.0f);
                float v1 = fmaxf(acc[i][j][1] + b4[1], 0.0f);
                float v2 = fmaxf(acc[i][j][2] + b4[2], 0.0f);
                float v3 = fmaxf(acc[i][j][3] + b4[3], 0.0f);
                int p = __builtin_amdgcn_cvt_pk_fp8_f32(v0, v1, 0, false);
                p     = __builtin_amdgcn_cvt_pk_fp8_f32(v2, v3, p, true);
                int idx = (((wm * 4 + i) * 4 + (j >> 1)) * 16 + r16) * 32
                        + (j & 1) * 16 + q * 4;
                *(int*)(eb + idx) = p;
            }
        }
        __syncthreads();
#pragma unroll
        for (int rd = 0; rd < 8; rd++) {
            int g2  = rd * 256 + t;            // dwordx4 index 0..2047
            int seg = g2 >> 5, off = (g2 & 31) * 16;
            int m16l = seg >> 2, c32l = seg & 3;
            i32x4 v = *(const i32x4*)(eb + seg * 512 + off);
            *(i32x4*)(O + ((size_t)((bm * 16 + m16l) * 32 + bn * 4 + c32l)) * 512 + off) = v;
        }
    } else {
#pragma unroll
        for (int i = 0; i < 4; i++) {
            float p0 = 0.f, p1 = 0.f, p2 = 0.f;
#pragma unroll
            for (int j = 0; j < 8; j++) {
                int nb = bn * 128 + j * 16 + q * 4;
                f32x4 b4 = *(const f32x4*)(bb + nb);
#pragma unroll
                for (int r = 0; r < 4; r++) {
                    float val = fmaxf(acc[i][j][r] + b4[r], 0.0f);
                    const float* w = Wout + (size_t)(nb + r) * NV;
                    p0 += val * w[0]; p1 += val * w[1]; p2 += val * w[2];
                }
            }
            // reduce over the 4 q-lanes (lane bits 4,5) holding the same m
            p0 += __shfl_xor(p0, 16); p0 += __shfl_xor(p0, 32);
            p1 += __shfl_xor(p1, 16); p1 += __shfl_xor(p1, 32);
            p2 += __shfl_xor(p2, 16); p2 += __shfl_xor(p2, 32);
            if (q == 0) {
                int m = bm * 256 + wm * 64 + i * 16 + r16;
                atomicAdd(&out[(size_t)m * NV + 0], p0);
                atomicAdd(&out[(size_t)m * NV + 1], p1);
                atomicAdd(&out[(size_t)m * NV + 2], p2);
            }
        }
    }
}

// ---------------------------------------------------------------------------
extern "C" void kernel_launch(void* const* d_in, const int* in_sizes, int n_in,
                              void* d_out, int out_size, void* d_ws, size_t ws_size,
                              hipStream_t stream) {
    const float* coords     = (const float*)d_in[0];
    const int*   latent_idx = (const int*)d_in[1];
    const float* latents    = (const float*)d_in[2];
    const float* codebooks  = (const float*)d_in[3];
    const float* mod_W      = (const float*)d_in[4];
    const float* mod_b      = (const float*)d_in[5];
    const float* dec_W0     = (const float*)d_in[6];
    const float* dec_b0     = (const float*)d_in[7];
    const float* dec_Wh     = (const float*)d_in[8];
    const float* dec_bh     = (const float*)d_in[9];
    const float* dec_Wout   = (const float*)d_in[10];
    const float* dec_bout   = (const float*)d_in[11];
    float* out = (float*)d_out;

    // ---- workspace layout (fixed part ~4.35 MB) ----
    char* wsb = (char*)d_ws;
    float* zq  = (float*)(wsb + 0);                        //      256 B
    float* bb  = (float*)(wsb + 256);                      //   20,480 B
    u8*    W0T = (u8*)(wsb + 20736);                       //  131,072 B  tiled
    u8*    WhT = (u8*)(wsb + 151808);                      // 4,194,304 B tiled
    const size_t fixed_end = 4346368;                      // 256-aligned

    // adaptive chunk: cap 65536 (single chunk, ws ~139 MB), halve until fits;
    // floor 2048 so Mb = Bc/256 stays a multiple of 8 (capture-safe).
    int Bc = 65536;
    while (Bc > 2048 && fixed_end + 2 * (size_t)Bc * NH > ws_size)
        Bc >>= 1;
    int Mb = Bc / 256;   // m-tiles of 256

    u8* hA = (u8*)(wsb + fixed_end);                       // [Bc][1024] fp8 A_t
    u8* hB = hA + (size_t)Bc * NH;                         // [Bc][1024] fp8 A_t
    u8* pe = hB;   // pe A_t [Bc][128] aliases hB (dead before layer-1 writes hB)

    // ---- one-time (per call) small kernels ----
    vq_kernel<<<1, 1024, 0, stream>>>(latents, latent_idx, codebooks, zq, out);
    betas_kernel<<<20, 256, 0, stream>>>(zq, mod_W, mod_b, dec_b0, dec_bh, bb);
    init_out_kernel<<<(NB * NV) / 256, 256, 0, stream>>>(dec_bout, out);
    prep_kernel<<<dim3(4, 32, 1), dim3(32, 8), 0, stream>>>(dec_W0, W0T, NIN, K0P);
    prep_kernel<<<dim3(32, 32, 4), dim3(32, 8), 0, stream>>>(dec_Wh, WhT, NH, NH);

    // ---- chunked 5-layer MLP, output layer fused into the last GEMM ----
    for (int c0 = 0; c0 < NB; c0 += Bc) {
        pe_kernel<<<(Bc * 32) / 256, 256, 0, stream>>>(coords + (size_t)c0 * NC, pe);
        gemm_kernel<0, K0P><<<8 * Mb, 256, 0, stream>>>(
            pe, W0T, bb + 0 * NH, hA, nullptr, nullptr, Mb);
        gemm_kernel<0, NH><<<8 * Mb, 256, 0, stream>>>(
            hA, WhT + 0 * (size_t)NH * NH, bb + 1 * NH, hB, nullptr, nullptr, Mb);
        gemm_kernel<0, NH><<<8 * Mb, 256, 0, stream>>>(
            hB, WhT + 1 * (size_t)NH * NH, bb + 2 * NH, hA, nullptr, nullptr, Mb);
        gemm_kernel<0, NH><<<8 * Mb, 256, 0, stream>>>(
            hA, WhT + 2 * (size_t)NH * NH, bb + 3 * NH, hB, nullptr, nullptr, Mb);
        gemm_kernel<1, NH><<<8 * Mb, 256, 0, stream>>>(
            hB, WhT + 3 * (size_t)NH * NH, bb + 4 * NH, nullptr,
            dec_Wout, out + (size_t)c0 * NV, Mb);
    }
}

// Round 9
// 466.634 us; speedup vs baseline: 1.8133x; 1.6807x over previous
//
#include <hip/hip_runtime.h>
#include <hip/hip_bf16.h>
#include <stdint.h>

// ---- problem constants ----
#define NB   65536      // batch points
#define NC   2
#define NV   3
#define ND   64
#define NK   1024       // codebook entries
#define NS   4
#define NH   1024
#define NL   5
#define NF   25
#define NIN  102
#define K0P  128        // padded layer-0 K

typedef float f32x4  __attribute__((ext_vector_type(4)));
typedef float f32x16 __attribute__((ext_vector_type(16)));
typedef int   i32x4  __attribute__((ext_vector_type(4)));
typedef int   i32x8  __attribute__((ext_vector_type(8)));
typedef unsigned char u8;

__device__ __forceinline__ void load_lds16(const void* g, void* l) {
    __builtin_amdgcn_global_load_lds(
        (const __attribute__((address_space(1))) void*)g,
        (__attribute__((address_space(3))) void*)l,
        16, 0, 0);
}

// fp8 e4m3 scalar convert (RNE, saturating): low byte of cvt_pk
__device__ __forceinline__ u8 to_fp8(float x) {
    return (u8)(__builtin_amdgcn_cvt_pk_fp8_f32(x, 0.0f, 0, false) & 0xff);
}

// 32x32x64 MX-fp8 MFMA. Swapped operands: src0 = W (n-dim on D "rows"),
// src1 = A (m-dim on D "cols"). D: col = lane&31 (m), row(n) =
// (reg&3) + 8*(reg>>2) + 4*(lane>>5), reg in [0,16).
__device__ __forceinline__ f32x16 mfma32(i32x8 wf, i32x8 af, f32x16 c) {
    return __builtin_amdgcn_mfma_scale_f32_32x32x64_f8f6f4(
        wf, af, c, 0, 0,
        0, 0x79797979,    // scale src0 (W): 2^-6
        0, 0x7f7f7f7f);   // scale src1 (A): 2^0
}

// ===========================================================================
// TILED OPERAND LAYOUTS (R21 — 32x32x64 fragments, half-split for stride-16)
// Fragment need (both operands): lane l holds X[row = 32-tile + (l&31)]
//   [k = ks*64 + (l>>5)*32 + 0..31], i.e. kh = l>>5, r32 = l&31, 32 k-bytes.
// Half-split storage of each (tile, ks) 2 KB chunk: [h(2)][kh(2)][r32(32)]
//   [b16(16)], h = upper/lower 16 of the 32 k-bytes. Then lane l reads
//   lo = chunk + l*16, hi = chunk + 1024 + l*16 (both stride-16: conflict-
//   free ds_read_b128 / fully-coalesced global dwordx4).
//  W_t: per bn (128 n): [ks(K/64)][j32(4)][h][kh][r32][b16]
//       -> per-(bn, 128-K iter) slab = 16 KB contiguous (2 ks) for staging.
//  A_t: [m32][ks(K/64)][h][kh][r32][b16] -> 2 KB chunk per (m32, ks).
// ===========================================================================

// ---------------------------------------------------------------------------
// VQ kernel: single block, 1024 threads (one codebook row per thread). fp32.
// ---------------------------------------------------------------------------
__global__ __launch_bounds__(1024) void vq_kernel(
    const float* __restrict__ latents, const int* __restrict__ latent_idx,
    const float* __restrict__ codebooks, float* __restrict__ zq_out,
    float* __restrict__ out) {
    __shared__ float zcur[ND], resid[ND], zqsum[ND], ssq[ND];
    __shared__ float sDw[16];
    __shared__ int   sKw[16];
    __shared__ int   sBest;
    int t = threadIdx.x, lane = t & 63, wv = t >> 6;
    const float* img = latents + (size_t)latent_idx[0] * (NS * ND);
    if (t < ND) { resid[t] = 0.f; zqsum[t] = 0.f; }
    __syncthreads();
    float lossAcc = 0.f;   // thread 0 only
    for (int s = 0; s < NS; s++) {
        if (t < ND) {
            float iv = img[s * ND + t];
            float r  = resid[t] + iv;
            resid[t] = r;
            zcur[t]  = (s == 0) ? iv : (r - zqsum[t]);
        }
        __syncthreads();
        float zz = 0.f;
#pragma unroll
        for (int d = 0; d < ND; d++) { float z = zcur[d]; zz += z * z; }
        const float4* e4 = (const float4*)(codebooks + ((size_t)s * NK + t) * ND);
        float dot = 0.f, ee = 0.f;
#pragma unroll
        for (int i = 0; i < 16; i++) {
            float4 v = e4[i];
            dot += zcur[4 * i + 0] * v.x; dot += zcur[4 * i + 1] * v.y;
            dot += zcur[4 * i + 2] * v.z; dot += zcur[4 * i + 3] * v.w;
            ee  += v.x * v.x; ee += v.y * v.y; ee += v.z * v.z; ee += v.w * v.w;
        }
        float dmin = zz - 2.0f * dot + ee;
        int   kmin = t;
#pragma unroll
        for (int m = 1; m < 64; m <<= 1) {
            float d2 = __shfl_xor(dmin, m);
            int   k2 = __shfl_xor(kmin, m);
            if (d2 < dmin || (d2 == dmin && k2 < kmin)) { dmin = d2; kmin = k2; }
        }
        if (lane == 0) { sDw[wv] = dmin; sKw[wv] = kmin; }
        __syncthreads();
        if (t == 0) {
            float bd = sDw[0]; int bk = sKw[0];
            for (int w = 1; w < 16; w++) {
                float d2 = sDw[w]; int k2 = sKw[w];
                if (d2 < bd || (d2 == bd && k2 < bk)) { bd = d2; bk = k2; }
            }
            sBest = bk;
            out[NB * NV + s] = (float)bk;
        }
        __syncthreads();
        int best = sBest;
        const float* eb = codebooks + ((size_t)s * NK + best) * ND;
        if (t < ND) {
            float zq = eb[t];
            float d  = zq - zcur[t];
            ssq[t]   = d * d;
            zqsum[t] = zqsum[t] + (zq + (zcur[t] - zq));   // z_q_st forward (exact ref arith)
        }
        __syncthreads();
        if (t == 0) {
            float sum = 0.f;
            for (int d = 0; d < ND; d++) sum += ssq[d];
            lossAcc += 0.25f * (sum / (float)ND);
        }
    }
    if (t < ND) zq_out[t] = zqsum[t];
    if (t == 0) out[NB * NV + NS] = lossAcc;
}

// ---------------------------------------------------------------------------
// betas fused with decoder biases (fp32)
// ---------------------------------------------------------------------------
__global__ __launch_bounds__(256) void betas_kernel(
    const float* __restrict__ zq, const float* __restrict__ mod_W,
    const float* __restrict__ mod_b, const float* __restrict__ b0,
    const float* __restrict__ bh, float* __restrict__ bb) {
    int g = blockIdx.x * 256 + threadIdx.x;   // < 5120
    int l = g >> 10, n = g & 1023;
    float acc = mod_b[g];
    for (int d = 0; d < ND; d++) acc += zq[d] * mod_W[(size_t)(l * ND + d) * NH + n];
    acc += (l == 0) ? b0[n] : bh[(size_t)(l - 1) * NH + n];
    bb[g] = acc;
}

// ---------------------------------------------------------------------------
// out init: values[m][v] = bout[v] (atomic-add target for the fused layer)
// ---------------------------------------------------------------------------
__global__ __launch_bounds__(256) void init_out_kernel(
    const float* __restrict__ bout, float* __restrict__ out) {
    int g = blockIdx.x * 256 + threadIdx.x;   // < NB*NV
    out[g] = bout[g % NV];
}

// ---------------------------------------------------------------------------
// Weight prep: fp32 [Ks][1024] -> fp8 e4m3 W_t (32x32x64 half-split tiling,
// x64 scale undone by the MFMA e8m0 scale 2^-6). Zero-pad k>=Ks.
// ---------------------------------------------------------------------------
__global__ __launch_bounds__(256) void prep_kernel(
    const float* __restrict__ src, u8* __restrict__ dst, int Ks, int Kp) {
    __shared__ float tile[32][33];
    src += (size_t)blockIdx.z * Ks * NH;
    dst += (size_t)blockIdx.z * NH * Kp;
    int k0 = blockIdx.x * 32, n0 = blockIdx.y * 32;
    int tx = threadIdx.x, ty = threadIdx.y;   // (32, 8)
    for (int i = 0; i < 4; i++) {
        int k = k0 + ty + i * 8;
        int n = n0 + tx;
        tile[ty + i * 8][tx] = (k < Ks) ? src[(size_t)k * NH + n] : 0.0f;
    }
    __syncthreads();
    for (int i = 0; i < 4; i++) {
        int n = n0 + ty + i * 8;
        int k = k0 + tx;
        int bn = n >> 7, j32 = (n >> 5) & 3, r32 = n & 31;
        int ks = k >> 6, kh = (k >> 5) & 1, h = (k >> 4) & 1, b16 = k & 15;
        size_t flat = (size_t)bn * ((size_t)Kp * 128)
                    + ((size_t)(((ks * 4 + j32) * 2 + h) * 2 + kh) * 32 + r32) * 16 + b16;
        dst[flat] = to_fp8(tile[tx][ty + i * 8] * 64.0f);
    }
}

// ---------------------------------------------------------------------------
// Positional encoding -> fp8 A_t (32x32x64 half-split, K=128 -> ks in {0,1})
// ---------------------------------------------------------------------------
__device__ __forceinline__ float pe_val(const float* coords, int m, int k) {
    if (k < 2) return coords[m * 2 + k];
    if (k >= NIN) return 0.0f;
    int u = k - 2;
    int f = u >> 2, r = u & 3;
    float c = coords[m * 2 + (r & 1)];
    float a = c * __builtin_ldexpf(3.14159274101257324f, f);
    return (r < 2) ? sinf(a) : cosf(a);
}

__global__ __launch_bounds__(256) void pe_kernel(
    const float* __restrict__ coords, u8* __restrict__ pe) {
    int g = blockIdx.x * 256 + threadIdx.x;   // < Bc*32
    int m = g >> 5, k4 = (g & 31) * 4;
    float v0 = pe_val(coords, m, k4 + 0);
    float v1 = pe_val(coords, m, k4 + 1);
    float v2 = pe_val(coords, m, k4 + 2);
    float v3 = pe_val(coords, m, k4 + 3);
    int p = __builtin_amdgcn_cvt_pk_fp8_f32(v0, v1, 0, false);
    p     = __builtin_amdgcn_cvt_pk_fp8_f32(v2, v3, p, true);
    int m32 = m >> 5, r32 = m & 31;
    int ks = k4 >> 6, kh = (k4 >> 5) & 1, h = (k4 >> 4) & 1, b16 = k4 & 15;
    *(int*)(pe + (size_t)(m32 * 2 + ks) * 2048
            + ((h * 2 + kh) * 32 + r32) * 16 + b16) = p;
}

// ---------------------------------------------------------------------------
// MX-fp8 MFMA GEMM, R21: R12's verified skeleton, 32x32x64 instruction.
// Rationale: R12/R15/R17 (3 schedules) all pin at MfmaUtil 25-30%; R13/14/
// 19/20 spilled (register budget has no slack at this tile). The untouched
// axis is the MFMA shape: 32x32x64 does 131072 FLOP/issue (2x 16x16x128 at
// the same TF rate) -> HALVES per-FLOP ds_read, A-load and VALU packing,
// which is exactly what the counters flag (VALUBusy ~27% ~ 1:1 with MFMA).
// Same 8-VGPR operands, same 128-AGPR accumulator (8 x f32x16): register
// budget isomorphic to R12 (124 VGPR, no spill).
// Structure (R12 verbatim): 256m x 128n block, 4 waves of 64m x 128n
// (2 m-tiles x 4 n-tiles of 32), 256 thr, launch_bounds(256,2), W via
// 2 x 16 KB LDS dbuf staged per 128-K iter, A direct global->reg, ONE
// __syncthreads per iter. All frag accesses stride-16 (half-split layouts).
// MODE 0: relu(acc+bb) -> fp8, repack to next layer's A_t via LDS, coalesced.
// MODE 1: out[m][v] += relu(acc+bb).Wout[n][v], lane^32 shfl + atomicAdd.
// ---------------------------------------------------------------------------
template <int MODE, int KT>
__global__ __launch_bounds__(256, 2) void gemm_kernel(
    const u8* __restrict__ A, const u8* __restrict__ W,
    const float* __restrict__ bb, u8* __restrict__ O,
    const float* __restrict__ Wout, float* __restrict__ out, int Mb) {
    __shared__ __align__(16) u8 smem[32768];
    int t   = threadIdx.x;
    int fid = blockIdx.x;
    int xcd = fid & 7;
    int j8  = fid >> 3;                 // 0..Mb-1
    int bn  = j8 & 7;                   // fastest within an XCD
    int bm  = xcd * (Mb >> 3) + (j8 >> 3);
    int lane = t & 63, wm = t >> 6;     // wave owns m-slice wm*64..+63
    int r32  = lane & 31, hl = lane >> 5;
    constexpr int nIt = KT >> 7;        // 128-K iters
    constexpr int nKs = KT >> 6;        // 64-K steps

    const u8* wslab = W + (size_t)bn * ((size_t)KT * 128);
    const u8* abase = A + ((size_t)(bm * 8 + wm * 2) * nKs) * 2048 + lane * 16;

    f32x16 acc[2][4];
#pragma unroll
    for (int i = 0; i < 2; i++)
#pragma unroll
        for (int j = 0; j < 4; j++)
#pragma unroll
            for (int e = 0; e < 16; e++) acc[i][j][e] = 0.0f;

    // A frags for k-step KS (global): dst[mt], 8 VGPR each
#define LOAD_AF(dst, KS)                                                       \
    {                                                                          \
        _Pragma("unroll")                                                      \
        for (int mt = 0; mt < 2; mt++) {                                       \
            const u8* p = abase + ((size_t)mt * nKs + (KS)) * 2048;            \
            i32x4 lo = *(const i32x4*)(p);                                     \
            i32x4 hi = *(const i32x4*)(p + 1024);                              \
            dst[mt] = __builtin_shufflevector(lo, hi, 0, 1, 2, 3, 4, 5, 6, 7); \
        }                                                                      \
    }
    // one 64-K half of an iter: 4 W-frag reads + 8 MFMA
#define MFMA_HALF(base, KSL, AF)                                               \
    {                                                                          \
        _Pragma("unroll")                                                      \
        for (int j = 0; j < 4; j++) {                                          \
            const u8* c = (base) + (KSL) * 8192 + j * 2048 + lane * 16;        \
            i32x4 lo = *(const i32x4*)(c);                                     \
            i32x4 hi = *(const i32x4*)(c + 1024);                              \
            i32x8 wf = __builtin_shufflevector(lo, hi, 0, 1, 2, 3, 4, 5, 6, 7);\
            acc[0][j] = mfma32(wf, AF[0], acc[0][j]);                          \
            acc[1][j] = mfma32(wf, AF[1], acc[1][j]);                          \
        }                                                                      \
    }

    if constexpr (nIt == 1) {
        // ---- K0P path: single 16 KB slab, both 64-K halves ----
#pragma unroll
        for (int p = 0; p < 4; p++) {
            int g = p * 256 + t;
            load_lds16((const void*)(wslab + g * 16), (void*)(smem + g * 16));
        }
        i32x8 af0[2], af1[2];
        LOAD_AF(af0, 0)
        LOAD_AF(af1, 1)
        __syncthreads();   // drains W staging + A loads
        MFMA_HALF(smem, 0, af0)
        MFMA_HALF(smem, 1, af1)
        __syncthreads();
    } else {
        // ---- prologue: stage W(it=0) into buf0; load A(ks=0,1) ----
#pragma unroll
        for (int p = 0; p < 4; p++) {
            int g = p * 256 + t;
            load_lds16((const void*)(wslab + g * 16), (void*)(smem + g * 16));
        }
        i32x8 afc0[2], afc1[2], afn0[2], afn1[2];
        LOAD_AF(afc0, 0)
        LOAD_AF(afc1, 1)
        __syncthreads();   // drains W staging + A loads

#pragma unroll 1
        for (int it = 0; it < nIt; it++) {
            u8* bufc = smem + ((it & 1) ? 16384 : 0);
            u8* bufn = smem + ((it & 1) ? 0 : 16384);
            // issue next-iter loads FIRST (consumed after this iter's barrier)
            if (it + 1 < nIt) {
                const u8* ws = wslab + (size_t)(it + 1) * 16384;
#pragma unroll
                for (int p = 0; p < 4; p++) {
                    int g = p * 256 + t;
                    load_lds16((const void*)(ws + g * 16), (void*)(bufn + g * 16));
                }
                LOAD_AF(afn0, 2 * (it + 1))
                LOAD_AF(afn1, 2 * (it + 1) + 1)
            }
            // compute current iter (16 x 32x32x64 MFMA)
            MFMA_HALF(bufc, 0, afc0)
            MFMA_HALF(bufc, 1, afc1)
            __syncthreads();   // drain: next W staged, next A landed, buf free
#pragma unroll
            for (int mt = 0; mt < 2; mt++) { afc0[mt] = afn0[mt]; afc1[mt] = afn1[mt]; }
        }
    }
#undef LOAD_AF
#undef MFMA_HALF

    // lane element (mt, nt, reg): m = bm*256 + wm*64 + mt*32 + r32,
    //   n = bn*128 + nt*32 + (reg&3) + 8*(reg>>2) + 4*hl
    if constexpr (MODE == 0) {
        // Repack to next layer's A_t (K'=NH): eb = [seg(16)=m32l*2+ksl][2 KB]
        u8* eb = smem;
#pragma unroll
        for (int mt = 0; mt < 2; mt++) {
#pragma unroll
            for (int nt = 0; nt < 4; nt++) {
                int kh  = nt & 1;
                int seg = (wm * 2 + mt) * 2 + (nt >> 1);
#pragma unroll
                for (int g = 0; g < 4; g++) {
                    int nbase = nt * 32 + 8 * g + 4 * hl;
                    f32x4 b4 = *(const f32x4*)(bb + bn * 128 + nbase);
                    float v0 = fmaxf(acc[mt][nt][4 * g + 0] + b4[0], 0.0f);
                    float v1 = fmaxf(acc[mt][nt][4 * g + 1] + b4[1], 0.0f);
                    float v2 = fmaxf(acc[mt][nt][4 * g + 2] + b4[2], 0.0f);
                    float v3 = fmaxf(acc[mt][nt][4 * g + 3] + b4[3], 0.0f);
                    int p = __builtin_amdgcn_cvt_pk_fp8_f32(v0, v1, 0, false);
                    p     = __builtin_amdgcn_cvt_pk_fp8_f32(v2, v3, p, true);
                    int h   = g >> 1;
                    int idx = seg * 2048 + ((h * 2 + kh) * 32 + r32) * 16
                            + ((8 * g + 4 * hl) & 15);
                    *(int*)(eb + idx) = p;
                }
            }
        }
        __syncthreads();
#pragma unroll
        for (int rd = 0; rd < 8; rd++) {
            int g2  = rd * 256 + t;            // dwordx4 index 0..2047
            int seg = g2 >> 7, off = (g2 & 127) * 16;
            int m32l = seg >> 1, ksl = seg & 1;
            i32x4 v = *(const i32x4*)(eb + seg * 2048 + off);
            *(i32x4*)(O + ((size_t)((bm * 8 + m32l) * (NH >> 6) + bn * 2 + ksl)) * 2048
                      + off) = v;
        }
    } else {
#pragma unroll
        for (int mt = 0; mt < 2; mt++) {
            float p0 = 0.f, p1 = 0.f, p2 = 0.f;
#pragma unroll
            for (int nt = 0; nt < 4; nt++) {
#pragma unroll
                for (int g = 0; g < 4; g++) {
                    int nbase = bn * 128 + nt * 32 + 8 * g + 4 * hl;
                    f32x4 b4 = *(const f32x4*)(bb + nbase);
#pragma unroll
                    for (int rr = 0; rr < 4; rr++) {
                        float val = fmaxf(acc[mt][nt][4 * g + rr] + b4[rr], 0.0f);
                        const float* wo = Wout + (size_t)(nbase + rr) * NV;
                        p0 += val * wo[0]; p1 += val * wo[1]; p2 += val * wo[2];
                    }
                }
            }
            // lane l and l^32 hold the complementary n-halves of the same m
            p0 += __shfl_xor(p0, 32);
            p1 += __shfl_xor(p1, 32);
            p2 += __shfl_xor(p2, 32);
            if (hl == 0) {
                int m = bm * 256 + wm * 64 + mt * 32 + r32;
                atomicAdd(&out[(size_t)m * NV + 0], p0);
                atomicAdd(&out[(size_t)m * NV + 1], p1);
                atomicAdd(&out[(size_t)m * NV + 2], p2);
            }
        }
    }
}

// ---------------------------------------------------------------------------
extern "C" void kernel_launch(void* const* d_in, const int* in_sizes, int n_in,
                              void* d_out, int out_size, void* d_ws, size_t ws_size,
                              hipStream_t stream) {
    const float* coords     = (const float*)d_in[0];
    const int*   latent_idx = (const int*)d_in[1];
    const float* latents    = (const float*)d_in[2];
    const float* codebooks  = (const float*)d_in[3];
    const float* mod_W      = (const float*)d_in[4];
    const float* mod_b      = (const float*)d_in[5];
    const float* dec_W0     = (const float*)d_in[6];
    const float* dec_b0     = (const float*)d_in[7];
    const float* dec_Wh     = (const float*)d_in[8];
    const float* dec_bh     = (const float*)d_in[9];
    const float* dec_Wout   = (const float*)d_in[10];
    const float* dec_bout   = (const float*)d_in[11];
    float* out = (float*)d_out;

    // ---- workspace layout (fixed part ~4.35 MB) ----
    char* wsb = (char*)d_ws;
    float* zq  = (float*)(wsb + 0);                        //      256 B
    float* bb  = (float*)(wsb + 256);                      //   20,480 B
    u8*    W0T = (u8*)(wsb + 20736);                       //  131,072 B  tiled
    u8*    WhT = (u8*)(wsb + 151808);                      // 4,194,304 B tiled
    const size_t fixed_end = 4346368;                      // 256-aligned

    // adaptive chunk: cap 65536 (single chunk, ws ~139 MB), halve until fits;
    // floor 2048 so Mb = Bc/256 stays a multiple of 8 (capture-safe).
    int Bc = 65536;
    while (Bc > 2048 && fixed_end + 2 * (size_t)Bc * NH > ws_size)
        Bc >>= 1;
    int Mb = Bc / 256;   // m-tiles of 256

    u8* hA = (u8*)(wsb + fixed_end);                       // [Bc][1024] fp8 A_t
    u8* hB = hA + (size_t)Bc * NH;                         // [Bc][1024] fp8 A_t
    u8* pe = hB;   // pe A_t [Bc][128] aliases hB (dead before layer-1 writes hB)

    // ---- one-time (per call) small kernels ----
    vq_kernel<<<1, 1024, 0, stream>>>(latents, latent_idx, codebooks, zq, out);
    betas_kernel<<<20, 256, 0, stream>>>(zq, mod_W, mod_b, dec_b0, dec_bh, bb);
    init_out_kernel<<<(NB * NV) / 256, 256, 0, stream>>>(dec_bout, out);
    prep_kernel<<<dim3(4, 32, 1), dim3(32, 8), 0, stream>>>(dec_W0, W0T, NIN, K0P);
    prep_kernel<<<dim3(32, 32, 4), dim3(32, 8), 0, stream>>>(dec_Wh, WhT, NH, NH);

    // ---- chunked 5-layer MLP, output layer fused into the last GEMM ----
    for (int c0 = 0; c0 < NB; c0 += Bc) {
        pe_kernel<<<(Bc * 32) / 256, 256, 0, stream>>>(coords + (size_t)c0 * NC, pe);
        gemm_kernel<0, K0P><<<8 * Mb, 256, 0, stream>>>(
            pe, W0T, bb + 0 * NH, hA, nullptr, nullptr, Mb);
        gemm_kernel<0, NH><<<8 * Mb, 256, 0, stream>>>(
            hA, WhT + 0 * (size_t)NH * NH, bb + 1 * NH, hB, nullptr, nullptr, Mb);
        gemm_kernel<0, NH><<<8 * Mb, 256, 0, stream>>>(
            hB, WhT + 1 * (size_t)NH * NH, bb + 2 * NH, hA, nullptr, nullptr, Mb);
        gemm_kernel<0, NH><<<8 * Mb, 256, 0, stream>>>(
            hA, WhT + 2 * (size_t)NH * NH, bb + 3 * NH, hB, nullptr, nullptr, Mb);
        gemm_kernel<1, NH><<<8 * Mb, 256, 0, stream>>>(
            hB, WhT + 3 * (size_t)NH * NH, bb + 4 * NH, nullptr,
            dec_Wout, out + (size_t)c0 * NV, Mb);
    }
}